// Round 5
// baseline (560.395 us; speedup 1.0000x reference)
//
#include <hip/hip_runtime.h>

// VQ-VAE forward on MI355X (gfx950). N=32768 tokens, D=512, M=1024, H=512.
// R5: B operands (E split, W1T, W2T) are L2-resident and fragment-shaped in
// global memory -> read B fragments directly from L2, LDS only for the A
// (token) tile. B loads issued before __syncthreads so they overlap the
// global_load_lds drain. Memsets + small kernels fused (16 -> 12 dispatches).

#define N_TOK 32768

typedef __attribute__((ext_vector_type(8))) short short8;     // 8x16b = 4 VGPR
typedef _Float16 half8 __attribute__((ext_vector_type(8)));
typedef __attribute__((ext_vector_type(4))) float f32x4;

__device__ __forceinline__ f32x4 mfma16(short8 a, short8 b, f32x4 c) {
    return __builtin_amdgcn_mfma_f32_16x16x32_bf16(a, b, c, 0, 0, 0);
}
__device__ __forceinline__ f32x4 mfma16h(half8 a, half8 b, f32x4 c) {
    return __builtin_amdgcn_mfma_f32_16x16x32_f16(a, b, c, 0, 0, 0);
}

__device__ __forceinline__ void gl_lds16(const void* g, void* l) {
    __builtin_amdgcn_global_load_lds(
        (const __attribute__((address_space(1))) void*)g,
        (__attribute__((address_space(3))) void*)l, 16, 0, 0);
}

__device__ __forceinline__ unsigned short f2bf(float x) {   // RNE fp32->bf16
    unsigned u = __float_as_uint(x);
    u += 0x7fffu + ((u >> 16) & 1u);
    return (unsigned short)(u >> 16);
}
__device__ __forceinline__ float bf2f(unsigned short h) {
    return __uint_as_float(((unsigned)h) << 16);
}
__device__ __forceinline__ unsigned short f2h(float x) {    // RNE fp32->fp16
    union { _Float16 h; unsigned short u; } c;
    c.h = (_Float16)x;
    return c.u;
}
__device__ __forceinline__ float h2f(unsigned short u) {
    union { _Float16 h; unsigned short u; } c;
    c.u = u;
    return (float)c.h;
}

__device__ __forceinline__ float waveSum(float v) {
#pragma unroll
    for (int off = 32; off > 0; off >>= 1) v += __shfl_down(v, off, 64);
    return v;  // lane 0
}
__device__ __forceinline__ float xorSum(float v) {
#pragma unroll
    for (int off = 1; off < 64; off <<= 1) v += __shfl_xor(v, off);
    return v;  // all lanes
}

// Stage one 128x32 16-bit tile into LDS, chunk-swizzled layout [kb][128][8].
__device__ __forceinline__ void stage_tile128(const unsigned short* __restrict__ src,
                                              int r0, int k0, short* lds,
                                              int w, int lane) {
#pragma unroll
    for (int iss = 0; iss < 2; ++iss) {
        int L = (w << 11) + (iss << 10) + (lane << 4);  // byte offset in 8KB tile
        int kb = L >> 11, m = (L >> 4) & 127;
        gl_lds16(src + (((size_t)(r0 + m)) << 9) + k0 + (kb << 3), (char*)lds + L);
    }
}

// ---------------- prep: X -> Xf (fp16) + A1 = bf16(relu(ln1(x))) ----------
// Also initializes minpack (fused memset).
__global__ __launch_bounds__(256) void prep_x_kernel(
        const float* __restrict__ X, const float* __restrict__ g,
        const float* __restrict__ b, unsigned short* __restrict__ Xf,
        unsigned short* __restrict__ A1, unsigned long long* __restrict__ minpack) {
    int tid = threadIdx.x;
    if (tid < 4) minpack[(blockIdx.x << 2) + tid] = ~0ULL;
    int lane = tid & 63;
    int n = (blockIdx.x << 2) + (tid >> 6);
    const float* row = X + ((size_t)n << 9);
    float v[8]; float s = 0.f, ss = 0.f;
#pragma unroll
    for (int i = 0; i < 8; ++i) { v[i] = row[lane + (i << 6)]; s += v[i]; ss += v[i] * v[i]; }
    s = xorSum(s); ss = xorSum(ss);
    float mu = s * (1.f / 512.f);
    float rs = rsqrtf(ss * (1.f / 512.f) - mu * mu + 1e-5f);
#pragma unroll
    for (int i = 0; i < 8; ++i) {
        int c = lane + (i << 6);
        size_t o = ((size_t)n << 9) + c;
        float x = v[i];
        Xf[o] = f2h(x);
        float a = fmaxf((x - mu) * rs * g[c] + b[c], 0.f);
        A1[o] = f2bf(a);
    }
}

// ---------------- prep: Hb(bf16) -> A2 = bf16(relu(ln2(h))) ----------------
__global__ __launch_bounds__(256) void prep_h_kernel(
        const unsigned short* __restrict__ Hb, const float* __restrict__ g,
        const float* __restrict__ b, unsigned short* __restrict__ A2) {
    int lane = threadIdx.x & 63;
    int n = (blockIdx.x << 2) + (threadIdx.x >> 6);
    const unsigned short* row = Hb + ((size_t)n << 9);
    float v[8]; float s = 0.f, ss = 0.f;
#pragma unroll
    for (int i = 0; i < 8; ++i) { v[i] = bf2f(row[lane + (i << 6)]); s += v[i]; ss += v[i] * v[i]; }
    s = xorSum(s); ss = xorSum(ss);
    float mu = s * (1.f / 512.f);
    float rs = rsqrtf(ss * (1.f / 512.f) - mu * mu + 1e-5f);
#pragma unroll
    for (int i = 0; i < 8; ++i) {
        int c = lane + (i << 6);
        float a = fmaxf((v[i] - mu) * rs * g[c] + b[c], 0.f);
        A2[((size_t)n << 9) + c] = f2bf(a);
    }
}

// ---------------- prep: E -> Ehf,Elf (fp16, scaled x512) + e_sq*512 --------
// Also zeroes icounts+cursor (fused memset; contiguous 2048 ints).
__global__ __launch_bounds__(256) void prep_e_kernel(
        const float* __restrict__ E, unsigned short* __restrict__ Ehf,
        unsigned short* __restrict__ Elf, float* __restrict__ e_sq,
        int* __restrict__ izero) {
    if (blockIdx.x < 8) izero[(blockIdx.x << 8) + threadIdx.x] = 0;
    int lane = threadIdx.x & 63;
    int m = (blockIdx.x << 2) + (threadIdx.x >> 6);
    const float* row = E + ((size_t)m << 9);
    float ss = 0.f;
#pragma unroll
    for (int i = 0; i < 8; ++i) {
        int c = lane + (i << 6);
        float x = row[c];
        ss += x * x;
        float xs = x * 512.f;           // exact pow2 scale, dodges fp16 subnormals
        unsigned short h = f2h(xs);
        size_t o = ((size_t)m << 9) + c;
        Ehf[o] = h;
        Elf[o] = f2h(xs - h2f(h));
    }
    ss = xorSum(ss);
    if (lane == 0) e_sq[m] = ss * 512.f;  // scaled to match 512*(x.e)
}

// ---------------- prep: W1 and W2 fp32 -> WT bf16 (one launch) -------------
__global__ __launch_bounds__(256) void prep_wt_kernel(
        const float* __restrict__ W1, const float* __restrict__ W2,
        unsigned short* __restrict__ W1T, unsigned short* __restrict__ W2T) {
    __shared__ float t[32][33];
    int bx = blockIdx.x;
    const float* W = (bx < 16) ? W1 : W2;
    unsigned short* WT = (bx < 16) ? W1T : W2T;
    int Nw = (bx < 16) ? 512 : 1024;
    int n0 = ((bx < 16) ? bx : (bx - 16)) << 5, k0 = blockIdx.y << 5;
    int tx = threadIdx.x & 31, ty = threadIdx.x >> 5;
#pragma unroll
    for (int l = 0; l < 4; ++l)
        t[ty + (l << 3)][tx] = W[(size_t)(k0 + ty + (l << 3)) * Nw + n0 + tx];
    __syncthreads();
#pragma unroll
    for (int l = 0; l < 4; ++l)
        WT[(((size_t)(n0 + ty + (l << 3))) << 9) + k0 + tx] = f2bf(t[tx][ty + (l << 3)]);
}

// ---------------- distance MFMA (fp16 2-pass, B direct from L2) ------------
__device__ __forceinline__ unsigned long long packDist(float d, int m) {
    unsigned u = __float_as_uint(d);
    u = (u & 0x80000000u) ? ~u : (u | 0x80000000u);
    return ((unsigned long long)u << 32) | (unsigned)m;
}

__global__ __launch_bounds__(256) void dist_mfma_kernel(
        const unsigned short* __restrict__ Xf,
        const unsigned short* __restrict__ Ehf, const unsigned short* __restrict__ Elf,
        const float* __restrict__ e_sq, unsigned long long* __restrict__ minpack) {
    __shared__ __align__(16) short Axs[4096];   // 8 KB: A tile only
    int tid = threadIdx.x, lane = tid & 63, w = tid >> 6;
    int quad = lane >> 4, lanelo = lane & 15;
    int wm = w >> 1, wn = w & 1;
    int row0 = blockIdx.x << 7, m0 = blockIdx.y << 7;
    f32x4 acc[4][4];
#pragma unroll
    for (int i = 0; i < 4; ++i)
#pragma unroll
        for (int j = 0; j < 4; ++j) acc[i][j] = 0.f;

    size_t boff[4];
#pragma unroll
    for (int j = 0; j < 4; ++j) {
        int code = m0 + (wn << 6) + (j << 4) + lanelo;
        boff[j] = ((size_t)code << 9) + (quad << 3);
    }

    for (int k0 = 0; k0 < 512; k0 += 32) {
        stage_tile128(Xf, row0, k0, Axs, w, lane);
        half8 bh[4], bl[4];
#pragma unroll
        for (int j = 0; j < 4; ++j) {   // issued before barrier: overlaps drain
            bh[j] = __builtin_bit_cast(half8, *(const short8*)(Ehf + boff[j] + k0));
            bl[j] = __builtin_bit_cast(half8, *(const short8*)(Elf + boff[j] + k0));
        }
        __syncthreads();
        half8 av[4];
#pragma unroll
        for (int i = 0; i < 4; ++i) {
            int m = (wm << 6) + (i << 4) + lanelo;
            av[i] = __builtin_bit_cast(half8, *(const short8*)&Axs[(quad << 10) + (m << 3)]);
        }
#pragma unroll
        for (int i = 0; i < 4; ++i)
#pragma unroll
            for (int j = 0; j < 4; ++j) {
                acc[i][j] = mfma16h(av[i], bh[j], acc[i][j]);
                acc[i][j] = mfma16h(av[i], bl[j], acc[i][j]);
            }
        __syncthreads();
    }

    float esq[4];
#pragma unroll
    for (int j = 0; j < 4; ++j) esq[j] = e_sq[m0 + (wn << 6) + (j << 4) + lanelo];
#pragma unroll
    for (int i = 0; i < 4; ++i)
#pragma unroll
        for (int r = 0; r < 4; ++r) {
            unsigned long long best = ~0ULL;
#pragma unroll
            for (int j = 0; j < 4; ++j) {
                int code = m0 + (wn << 6) + (j << 4) + lanelo;
                float d = esq[j] - 2.f * acc[i][j][r];
                unsigned long long p = packDist(d, code);
                if (p < best) best = p;
            }
#pragma unroll
            for (int off = 1; off < 16; off <<= 1) {
                unsigned long long q = __shfl_xor(best, off);
                if (q < best) best = q;
            }
            if (lanelo == 0) {
                int t = row0 + (wm << 6) + (i << 4) + (quad << 2) + r;
                atomicMin(&minpack[t], best);
            }
        }
}

// ---------------- gather quantized + int counts + vq term ----------------
__global__ __launch_bounds__(256) void gather_kernel(
        const float* __restrict__ X, const float* __restrict__ E,
        const unsigned long long* __restrict__ minpack,
        float* __restrict__ out_q, int* __restrict__ icounts,
        float* __restrict__ vqsum) {
    int lane = threadIdx.x & 63;
    int n = (blockIdx.x << 2) + (threadIdx.x >> 6);
    int idx = (int)(minpack[n] & 0xFFFFFFFFULL);
    if (lane == 0) atomicAdd(&icounts[idx], 1);
    const float* xr = X + ((size_t)n << 9);
    const float* er = E + ((size_t)idx << 9);
    float s = 0.f;
#pragma unroll
    for (int i = 0; i < 8; ++i) {
        int c = lane + (i << 6);
        float xv = xr[c], q = er[c];
        out_q[((size_t)n << 9) + c] = q;
        float dlt = xv - q;
        s += dlt * dlt;
    }
    s = waveSum(s);
    if (lane == 0) vqsum[n] = 0.25f * s;
}

// ---------------- codebook: EMA smoothing + perplexity + bucket offsets ----
__global__ __launch_bounds__(1024) void codebook_kernel(
        const float* __restrict__ ema_count, const int* __restrict__ icounts,
        float* __restrict__ out_perp, float* __restrict__ out_newcount,
        int* __restrict__ offsets) {
    __shared__ int sc[1024];
    __shared__ float red[16];
    int tid = threadIdx.x;
    int lane = tid & 63, wid = tid >> 6;
    int ic = icounts[tid];
    sc[tid] = ic;
    for (int off = 1; off < 1024; off <<= 1) {
        __syncthreads();
        int v = (tid >= off) ? sc[tid - off] : 0;
        __syncthreads();
        sc[tid] += v;
    }
    offsets[tid] = sc[tid] - ic;
    __syncthreads();

    float cnt = (float)ic;
    float raw = 0.999f * ema_count[tid] + 0.001f * cnt;
    float v = waveSum(raw);
    if (lane == 0) red[wid] = v;
    __syncthreads();
    float nsum = 0.f;
#pragma unroll
    for (int i = 0; i < 16; ++i) nsum += red[i];
    __syncthreads();
    float p = cnt * (1.f / 32768.f);
    float e = p * logf(p + 1e-10f);
    e = waveSum(e);
    if (lane == 0) red[wid] = e;
    __syncthreads();
    float ent = 0.f;
#pragma unroll
    for (int i = 0; i < 16; ++i) ent += red[i];
    float nc = (raw + 1e-5f) / (nsum + 1024.f * 1e-5f) * nsum;
    out_newcount[tid] = nc;
    if (tid == 0) out_perp[0] = expf(-ent);
}

// ---------------- scatter: token n -> bucket of its code ----------------
__global__ __launch_bounds__(256) void scatter_kernel(
        const unsigned long long* __restrict__ minpack,
        const int* __restrict__ offsets, int* __restrict__ cursor,
        int* __restrict__ bucket) {
    int n = (blockIdx.x << 8) + threadIdx.x;
    int idx = (int)(minpack[n] & 0xFFFFFFFFULL);
    int pos = atomicAdd(&cursor[idx], 1);
    bucket[offsets[idx] + pos] = n;
}

// ---------------- dw[m] = sum of x rows in bucket m (dense reads) ----------
__global__ __launch_bounds__(256) void dw_kernel(
        const float* __restrict__ X, const int* __restrict__ bucket,
        const int* __restrict__ icounts, const int* __restrict__ offsets,
        float* __restrict__ dw) {
    __shared__ float comb[4][512];
    int tid = threadIdx.x, lane = tid & 63, w = tid >> 6;
    int m = blockIdx.x;
    int cnt = icounts[m], base = offsets[m];
    float acc[8] = {};
    for (int i = w; i < cnt; i += 4) {
        int t = bucket[base + i];
        const float* xr = X + ((size_t)t << 9);
#pragma unroll
        for (int j = 0; j < 8; ++j) acc[j] += xr[lane + (j << 6)];
    }
#pragma unroll
    for (int j = 0; j < 8; ++j) comb[w][lane + (j << 6)] = acc[j];
    __syncthreads();
    for (int c = tid; c < 512; c += 256)
        dw[((size_t)m << 9) + c] = comb[0][c] + comb[1][c] + comb[2][c] + comb[3][c];
}

// ---------------- GEMM1 MFMA: Hb = bf16(A1 @ W1T^T), B direct from L2 ------
__global__ __launch_bounds__(256) void gemm1_mfma_kernel(
        const unsigned short* __restrict__ A1, const unsigned short* __restrict__ W1T,
        unsigned short* __restrict__ Hb) {
    __shared__ __align__(16) short As[4096];
    int tid = threadIdx.x, lane = tid & 63, w = tid >> 6;
    int quad = lane >> 4, lanelo = lane & 15;
    int wm = w >> 1, wn = w & 1;
    int row0 = blockIdx.x << 7, n0 = blockIdx.y << 7;
    f32x4 acc[4][4];
#pragma unroll
    for (int i = 0; i < 4; ++i)
#pragma unroll
        for (int j = 0; j < 4; ++j) acc[i][j] = 0.f;

    size_t boff[4];
#pragma unroll
    for (int j = 0; j < 4; ++j)
        boff[j] = ((size_t)(n0 + (wn << 6) + (j << 4) + lanelo) << 9) + (quad << 3);

    for (int k0 = 0; k0 < 512; k0 += 32) {
        stage_tile128(A1, row0, k0, As, w, lane);
        short8 bf[4];
#pragma unroll
        for (int j = 0; j < 4; ++j) bf[j] = *(const short8*)(W1T + boff[j] + k0);
        __syncthreads();
        short8 af[4];
#pragma unroll
        for (int i = 0; i < 4; ++i) {
            int m = (wm << 6) + (i << 4) + lanelo;
            af[i] = *(const short8*)&As[(quad << 10) + (m << 3)];
        }
#pragma unroll
        for (int i = 0; i < 4; ++i)
#pragma unroll
            for (int j = 0; j < 4; ++j) acc[i][j] = mfma16(af[i], bf[j], acc[i][j]);
        __syncthreads();
    }
#pragma unroll
    for (int i = 0; i < 4; ++i)
#pragma unroll
        for (int j = 0; j < 4; ++j)
#pragma unroll
            for (int r = 0; r < 4; ++r) {
                int row = row0 + (wm << 6) + (i << 4) + (quad << 2) + r;
                int col = n0 + (wn << 6) + (j << 4) + lanelo;
                Hb[((size_t)row << 9) + col] = f2bf(acc[i][j][r]);
            }
}

// ---------------- GEMM2 chunk (B direct from L2) + softmax partials --------
__global__ __launch_bounds__(256) void gemm2_chunk_kernel(
        const unsigned short* __restrict__ A2, const unsigned short* __restrict__ W2T,
        const int* __restrict__ mask, const int* __restrict__ labels,
        float* __restrict__ ws_cmax, float* __restrict__ ws_csum,
        float* __restrict__ ws_lab) {
    __shared__ __align__(16) short As[4096];
    __shared__ float lmax[2][2][64], lsum[2][2][64], llab[128];
    __shared__ int slab[128];
    int tid = threadIdx.x, lane = tid & 63, w = tid >> 6;
    int quad = lane >> 4, lanelo = lane & 15;
    int wm = w >> 1, wn = w & 1;
    int row0 = blockIdx.x << 7, c0 = blockIdx.y << 7;
    if (tid < 128) {
        int mk = mask[row0 + tid];
        slab[tid] = mk ? 0 : labels[row0 + tid];  // safe label
    }
    f32x4 acc[4][4];
#pragma unroll
    for (int i = 0; i < 4; ++i)
#pragma unroll
        for (int j = 0; j < 4; ++j) acc[i][j] = 0.f;

    size_t boff[4];
#pragma unroll
    for (int j = 0; j < 4; ++j)
        boff[j] = ((size_t)(c0 + (wn << 6) + (j << 4) + lanelo) << 9) + (quad << 3);

    for (int k0 = 0; k0 < 512; k0 += 32) {
        stage_tile128(A2, row0, k0, As, w, lane);
        short8 bf[4];
#pragma unroll
        for (int j = 0; j < 4; ++j) bf[j] = *(const short8*)(W2T + boff[j] + k0);
        __syncthreads();
        short8 af[4];
#pragma unroll
        for (int i = 0; i < 4; ++i) {
            int m = (wm << 6) + (i << 4) + lanelo;
            af[i] = *(const short8*)&As[(quad << 10) + (m << 3)];
        }
#pragma unroll
        for (int i = 0; i < 4; ++i)
#pragma unroll
            for (int j = 0; j < 4; ++j) acc[i][j] = mfma16(af[i], bf[j], acc[i][j]);
        __syncthreads();
    }

    // label-logit capture (unique owner lane/reg)
#pragma unroll
    for (int i = 0; i < 4; ++i)
#pragma unroll
        for (int j = 0; j < 4; ++j)
#pragma unroll
            for (int r = 0; r < 4; ++r) {
                int code = c0 + (wn << 6) + (j << 4) + lanelo;
                int tt = (wm << 6) + (i << 4) + (quad << 2) + r;
                if (code == slab[tt]) llab[tt] = acc[i][j][r];
            }
#pragma unroll
    for (int i = 0; i < 4; ++i)
#pragma unroll
        for (int r = 0; r < 4; ++r) {
            float mx = fmaxf(fmaxf(acc[i][0][r], acc[i][1][r]),
                             fmaxf(acc[i][2][r], acc[i][3][r]));
#pragma unroll
            for (int off = 1; off < 16; off <<= 1) mx = fmaxf(mx, __shfl_xor(mx, off));
            if (lanelo == 0) lmax[wm][wn][(i << 4) + (quad << 2) + r] = mx;
        }
    __syncthreads();
#pragma unroll
    for (int i = 0; i < 4; ++i)
#pragma unroll
        for (int r = 0; r < 4; ++r) {
            int tl = (i << 4) + (quad << 2) + r;
            float cm = fmaxf(lmax[wm][0][tl], lmax[wm][1][tl]);
            float s = expf(acc[i][0][r] - cm) + expf(acc[i][1][r] - cm) +
                      expf(acc[i][2][r] - cm) + expf(acc[i][3][r] - cm);
#pragma unroll
            for (int off = 1; off < 16; off <<= 1) s += __shfl_xor(s, off);
            if (lanelo == 0) lsum[wm][wn][tl] = s;
        }
    __syncthreads();
    if (tid < 128) {
        int wmi = tid >> 6, tl = tid & 63;
        int token = row0 + tid;
        float cm = fmaxf(lmax[wmi][0][tl], lmax[wmi][1][tl]);
        float cs = lsum[wmi][0][tl] + lsum[wmi][1][tl];
        size_t o = ((size_t)blockIdx.y << 15) + token;  // [chunk][token]
        ws_cmax[o] = cm;
        ws_csum[o] = cs;
        if ((slab[tid] >> 7) == (int)blockIdx.y) ws_lab[token] = llab[tid];
    }
}

// ---------------- epilogue: new_weight/new_embedding + CE combine ----------
__global__ __launch_bounds__(256) void epilogue_kernel(
        const float* __restrict__ ema_weight, const float* __restrict__ dw,
        const float* __restrict__ newcount, float* __restrict__ out_neww,
        float* __restrict__ out_newemb,
        const float* __restrict__ ws_cmax, const float* __restrict__ ws_csum,
        const float* __restrict__ ws_lab, const int* __restrict__ mask,
        const float* __restrict__ vqsum, float* __restrict__ loss_out) {
    int bx = blockIdx.x;
    if (bx < 2048) {
        int i = (bx << 8) + threadIdx.x;
        float nw = 0.999f * ema_weight[i] + 0.001f * dw[i];
        out_neww[i] = nw;
        out_newemb[i] = nw / newcount[i >> 9];
    } else {
        int n = ((bx - 2048) << 8) + threadIdx.x;
        float m[8], s[8];
#pragma unroll
        for (int c = 0; c < 8; ++c) {
            m[c] = ws_cmax[(c << 15) + n];
            s[c] = ws_csum[(c << 15) + n];
        }
        float gm = m[0];
#pragma unroll
        for (int c = 1; c < 8; ++c) gm = fmaxf(gm, m[c]);
        float se = 0.f;
#pragma unroll
        for (int c = 0; c < 8; ++c) se += s[c] * expf(m[c] - gm);
        float ce = -(ws_lab[n] - gm - logf(se));
        loss_out[n] = (mask[n] ? 0.f : ce) + vqsum[n];
    }
}

extern "C" void kernel_launch(void* const* d_in, const int* in_sizes, int n_in,
                              void* d_out, int out_size, void* d_ws, size_t ws_size,
                              hipStream_t stream) {
    const float* X          = (const float*)d_in[0];
    const int*   mask       = (const int*)d_in[1];
    const int*   labels     = (const int*)d_in[2];
    const float* E          = (const float*)d_in[3];
    const float* ema_count  = (const float*)d_in[4];
    const float* ema_weight = (const float*)d_in[5];
    const float* g1 = (const float*)d_in[6];
    const float* b1 = (const float*)d_in[7];
    const float* W1 = (const float*)d_in[8];
    const float* g2 = (const float*)d_in[9];
    const float* b2 = (const float*)d_in[10];
    const float* W2 = (const float*)d_in[11];

    float* out = (float*)d_out;
    float* out_q        = out;              // 16777216
    float* out_loss     = out + 16777216;   // 32768
    float* out_perp     = out + 16809984;   // 1
    float* out_newemb   = out + 16809985;   // 524288
    float* out_newcount = out + 17334273;   // 1024
    float* out_neww     = out + 17335297;   // 524288

    float* w = (float*)d_ws;
    float* vqsum = w;  w += 32768;
    float* e_sq = w;   w += 1024;
    float* dwbuf = w;  w += 524288;
    unsigned long long* minpack = (unsigned long long*)w; w += 65536;
    float* ws_cmax = w; w += 262144;
    float* ws_csum = w; w += 262144;
    float* ws_lab  = w; w += 32768;
    int* icounts = (int*)w; w += 1024;      // icounts+cursor contiguous zero region
    int* cursor  = (int*)w; w += 1024;
    int* offsets = (int*)w; w += 1024;
    int* bucket  = (int*)w; w += 32768;
    unsigned short* Ehf = (unsigned short*)w; w += 262144;
    unsigned short* Elf = (unsigned short*)w; w += 262144;
    unsigned short* W1T = (unsigned short*)w; w += 131072;
    unsigned short* W2T = (unsigned short*)w; w += 262144;
    unsigned short* Xf  = (unsigned short*)w; w += 8388608;
    unsigned short* A1  = (unsigned short*)w; w += 8388608;
    unsigned short* Hb  = (unsigned short*)w; w += 8388608;
    unsigned short* A2  = Xf;   // alias: Xf dead after dist

    prep_e_kernel<<<256, 256, 0, stream>>>(E, Ehf, Elf, e_sq, icounts);
    prep_wt_kernel<<<dim3(48, 16), 256, 0, stream>>>(W1, W2, W1T, W2T);
    prep_x_kernel<<<8192, 256, 0, stream>>>(X, g1, b1, Xf, A1, minpack);
    dist_mfma_kernel<<<dim3(256, 8), 256, 0, stream>>>(Xf, Ehf, Elf, e_sq, minpack);
    gather_kernel<<<8192, 256, 0, stream>>>(X, E, minpack, out_q, icounts, vqsum);
    codebook_kernel<<<1, 1024, 0, stream>>>(ema_count, icounts, out_perp,
                                            out_newcount, offsets);
    scatter_kernel<<<128, 256, 0, stream>>>(minpack, offsets, cursor, bucket);
    dw_kernel<<<1024, 256, 0, stream>>>(X, bucket, icounts, offsets, dwbuf);
    gemm1_mfma_kernel<<<dim3(256, 4), 256, 0, stream>>>(A1, W1T, Hb);
    prep_h_kernel<<<8192, 256, 0, stream>>>(Hb, g2, b2, A2);
    gemm2_chunk_kernel<<<dim3(256, 8), 256, 0, stream>>>(A2, W2T, mask, labels,
                                                         ws_cmax, ws_csum, ws_lab);
    epilogue_kernel<<<2176, 256, 0, stream>>>(ema_weight, dwbuf, out_newcount,
                                              out_neww, out_newemb,
                                              ws_cmax, ws_csum, ws_lab,
                                              mask, vqsum, out_loss);
}

// Round 6
// 477.828 us; speedup vs baseline: 1.1728x; 1.1728x over previous
//
#include <hip/hip_runtime.h>

// VQ-VAE forward on MI355X (gfx950). N=32768 tokens, D=512, M=1024, H=512.
// R6: revert R5's direct-L2 B (regressed: scattered 16B L2 loads serialize
// vs MFMA). All MFMA kernels now use 2-deep ping-pong LDS pipeline with raw
// s_barrier + manual s_waitcnt vmcnt(N): next tile's global_load_lds issued
// BEFORE waiting on previous tile -> staging latency hidden behind MFMA.

#define N_TOK 32768
// s_waitcnt imm: vmcnt low nibble [3:0], expcnt=7 [6:4], lgkmcnt=15 [11:8]
#define WAITV(n) __builtin_amdgcn_s_waitcnt(0x0F70 | (n))
#define BAR() __builtin_amdgcn_s_barrier()

typedef __attribute__((ext_vector_type(8))) short short8;     // 8x16b = 4 VGPR
typedef _Float16 half8 __attribute__((ext_vector_type(8)));
typedef __attribute__((ext_vector_type(4))) float f32x4;

__device__ __forceinline__ f32x4 mfma16(short8 a, short8 b, f32x4 c) {
    return __builtin_amdgcn_mfma_f32_16x16x32_bf16(a, b, c, 0, 0, 0);
}
__device__ __forceinline__ f32x4 mfma16h(half8 a, half8 b, f32x4 c) {
    return __builtin_amdgcn_mfma_f32_16x16x32_f16(a, b, c, 0, 0, 0);
}

__device__ __forceinline__ void gl_lds16(const void* g, void* l) {
    __builtin_amdgcn_global_load_lds(
        (const __attribute__((address_space(1))) void*)g,
        (__attribute__((address_space(3))) void*)l, 16, 0, 0);
}

__device__ __forceinline__ unsigned short f2bf(float x) {   // RNE fp32->bf16
    unsigned u = __float_as_uint(x);
    u += 0x7fffu + ((u >> 16) & 1u);
    return (unsigned short)(u >> 16);
}
__device__ __forceinline__ float bf2f(unsigned short h) {
    return __uint_as_float(((unsigned)h) << 16);
}
__device__ __forceinline__ unsigned short f2h(float x) {    // RNE fp32->fp16
    union { _Float16 h; unsigned short u; } c;
    c.h = (_Float16)x;
    return c.u;
}
__device__ __forceinline__ float h2f(unsigned short u) {
    union { _Float16 h; unsigned short u; } c;
    c.u = u;
    return (float)c.h;
}

__device__ __forceinline__ float waveSum(float v) {
#pragma unroll
    for (int off = 32; off > 0; off >>= 1) v += __shfl_down(v, off, 64);
    return v;  // lane 0
}
__device__ __forceinline__ float xorSum(float v) {
#pragma unroll
    for (int off = 1; off < 64; off <<= 1) v += __shfl_xor(v, off);
    return v;  // all lanes
}

// Stage one 128x32 16-bit tile into LDS, chunk-swizzled layout [kb][128][8].
// 2 global_load_lds instructions per thread.
__device__ __forceinline__ void stage_tile128(const unsigned short* __restrict__ src,
                                              int r0, int k0, short* lds,
                                              int w, int lane) {
#pragma unroll
    for (int iss = 0; iss < 2; ++iss) {
        int L = (w << 11) + (iss << 10) + (lane << 4);  // byte offset in 8KB tile
        int kb = L >> 11, m = (L >> 4) & 127;
        gl_lds16(src + (((size_t)(r0 + m)) << 9) + k0 + (kb << 3), (char*)lds + L);
    }
}

// ---------------- prep: X -> Xf (fp16) + A1 = bf16(relu(ln1(x))) ----------
__global__ __launch_bounds__(256) void prep_x_kernel(
        const float* __restrict__ X, const float* __restrict__ g,
        const float* __restrict__ b, unsigned short* __restrict__ Xf,
        unsigned short* __restrict__ A1, unsigned long long* __restrict__ minpack) {
    int tid = threadIdx.x;
    if (tid < 4) minpack[(blockIdx.x << 2) + tid] = ~0ULL;
    int lane = tid & 63;
    int n = (blockIdx.x << 2) + (tid >> 6);
    const float* row = X + ((size_t)n << 9);
    float v[8]; float s = 0.f, ss = 0.f;
#pragma unroll
    for (int i = 0; i < 8; ++i) { v[i] = row[lane + (i << 6)]; s += v[i]; ss += v[i] * v[i]; }
    s = xorSum(s); ss = xorSum(ss);
    float mu = s * (1.f / 512.f);
    float rs = rsqrtf(ss * (1.f / 512.f) - mu * mu + 1e-5f);
#pragma unroll
    for (int i = 0; i < 8; ++i) {
        int c = lane + (i << 6);
        size_t o = ((size_t)n << 9) + c;
        float x = v[i];
        Xf[o] = f2h(x);
        float a = fmaxf((x - mu) * rs * g[c] + b[c], 0.f);
        A1[o] = f2bf(a);
    }
}

// ---------------- prep: Hb(bf16) -> A2 = bf16(relu(ln2(h))) ----------------
__global__ __launch_bounds__(256) void prep_h_kernel(
        const unsigned short* __restrict__ Hb, const float* __restrict__ g,
        const float* __restrict__ b, unsigned short* __restrict__ A2) {
    int lane = threadIdx.x & 63;
    int n = (blockIdx.x << 2) + (threadIdx.x >> 6);
    const unsigned short* row = Hb + ((size_t)n << 9);
    float v[8]; float s = 0.f, ss = 0.f;
#pragma unroll
    for (int i = 0; i < 8; ++i) { v[i] = bf2f(row[lane + (i << 6)]); s += v[i]; ss += v[i] * v[i]; }
    s = xorSum(s); ss = xorSum(ss);
    float mu = s * (1.f / 512.f);
    float rs = rsqrtf(ss * (1.f / 512.f) - mu * mu + 1e-5f);
#pragma unroll
    for (int i = 0; i < 8; ++i) {
        int c = lane + (i << 6);
        float a = fmaxf((v[i] - mu) * rs * g[c] + b[c], 0.f);
        A2[((size_t)n << 9) + c] = f2bf(a);
    }
}

// ---------------- prep: E -> Ehf,Elf (fp16, scaled x512) + e_sq*512 --------
__global__ __launch_bounds__(256) void prep_e_kernel(
        const float* __restrict__ E, unsigned short* __restrict__ Ehf,
        unsigned short* __restrict__ Elf, float* __restrict__ e_sq,
        int* __restrict__ izero) {
    if (blockIdx.x < 8) izero[(blockIdx.x << 8) + threadIdx.x] = 0;
    int lane = threadIdx.x & 63;
    int m = (blockIdx.x << 2) + (threadIdx.x >> 6);
    const float* row = E + ((size_t)m << 9);
    float ss = 0.f;
#pragma unroll
    for (int i = 0; i < 8; ++i) {
        int c = lane + (i << 6);
        float x = row[c];
        ss += x * x;
        float xs = x * 512.f;           // exact pow2 scale, dodges fp16 subnormals
        unsigned short h = f2h(xs);
        size_t o = ((size_t)m << 9) + c;
        Ehf[o] = h;
        Elf[o] = f2h(xs - h2f(h));
    }
    ss = xorSum(ss);
    if (lane == 0) e_sq[m] = ss * 512.f;  // scaled to match 512*(x.e)
}

// ---------------- prep: W1 and W2 fp32 -> WT bf16 (one launch) -------------
__global__ __launch_bounds__(256) void prep_wt_kernel(
        const float* __restrict__ W1, const float* __restrict__ W2,
        unsigned short* __restrict__ W1T, unsigned short* __restrict__ W2T) {
    __shared__ float t[32][33];
    int bx = blockIdx.x;
    const float* W = (bx < 16) ? W1 : W2;
    unsigned short* WT = (bx < 16) ? W1T : W2T;
    int Nw = (bx < 16) ? 512 : 1024;
    int n0 = ((bx < 16) ? bx : (bx - 16)) << 5, k0 = blockIdx.y << 5;
    int tx = threadIdx.x & 31, ty = threadIdx.x >> 5;
#pragma unroll
    for (int l = 0; l < 4; ++l)
        t[ty + (l << 3)][tx] = W[(size_t)(k0 + ty + (l << 3)) * Nw + n0 + tx];
    __syncthreads();
#pragma unroll
    for (int l = 0; l < 4; ++l)
        WT[(((size_t)(n0 + ty + (l << 3))) << 9) + k0 + tx] = f2bf(t[tx][ty + (l << 3)]);
}

// ---------------- distance MFMA (fp16 2-pass, ping-pong LDS pipeline) ------
__device__ __forceinline__ unsigned long long packDist(float d, int m) {
    unsigned u = __float_as_uint(d);
    u = (u & 0x80000000u) ? ~u : (u | 0x80000000u);
    return ((unsigned long long)u << 32) | (unsigned)m;
}

__global__ __launch_bounds__(256) void dist_mfma_kernel(
        const unsigned short* __restrict__ Xf,
        const unsigned short* __restrict__ Ehf, const unsigned short* __restrict__ Elf,
        const float* __restrict__ e_sq, unsigned long long* __restrict__ minpack) {
    __shared__ __align__(16) short L[2][3][4096];   // 48 KB: 2 bufs x (A,Bh,Bl)
    int tid = threadIdx.x, lane = tid & 63, w = tid >> 6;
    int quad = lane >> 4, lanelo = lane & 15;
    int wm = w >> 1, wn = w & 1;
    int row0 = blockIdx.x << 7, m0 = blockIdx.y << 7;
    f32x4 acc[4][4];
#pragma unroll
    for (int i = 0; i < 4; ++i)
#pragma unroll
        for (int j = 0; j < 4; ++j) acc[i][j] = 0.f;

    // prologue: stage k0=0 into buf 0 (6 loads/thread)
    stage_tile128(Xf, row0, 0, L[0][0], w, lane);
    stage_tile128(Ehf, m0, 0, L[0][1], w, lane);
    stage_tile128(Elf, m0, 0, L[0][2], w, lane);

    for (int it = 0; it < 16; ++it) {
        if (it < 15) {   // prefetch next tile into other buffer, then wait
            int kn = (it + 1) << 5, nb = (it + 1) & 1;
            stage_tile128(Xf, row0, kn, L[nb][0], w, lane);
            stage_tile128(Ehf, m0, kn, L[nb][1], w, lane);
            stage_tile128(Elf, m0, kn, L[nb][2], w, lane);
            WAITV(6);    // only current tile must be complete
        } else {
            WAITV(0);
        }
        BAR();
        int cb = it & 1;
        half8 av[4], bh[4], bl[4];
#pragma unroll
        for (int i = 0; i < 4; ++i) {
            int m = (wm << 6) + (i << 4) + lanelo;
            av[i] = __builtin_bit_cast(half8, *(const short8*)&L[cb][0][(quad << 10) + (m << 3)]);
        }
#pragma unroll
        for (int j = 0; j < 4; ++j) {
            int n = (wn << 6) + (j << 4) + lanelo;
            bh[j] = __builtin_bit_cast(half8, *(const short8*)&L[cb][1][(quad << 10) + (n << 3)]);
            bl[j] = __builtin_bit_cast(half8, *(const short8*)&L[cb][2][(quad << 10) + (n << 3)]);
        }
#pragma unroll
        for (int i = 0; i < 4; ++i)
#pragma unroll
            for (int j = 0; j < 4; ++j) {
                acc[i][j] = mfma16h(av[i], bh[j], acc[i][j]);
                acc[i][j] = mfma16h(av[i], bl[j], acc[i][j]);
            }
        BAR();  // all waves done reading buf cb before it is restaged
    }

    float esq[4];
#pragma unroll
    for (int j = 0; j < 4; ++j) esq[j] = e_sq[m0 + (wn << 6) + (j << 4) + lanelo];
#pragma unroll
    for (int i = 0; i < 4; ++i)
#pragma unroll
        for (int r = 0; r < 4; ++r) {
            unsigned long long best = ~0ULL;
#pragma unroll
            for (int j = 0; j < 4; ++j) {
                int code = m0 + (wn << 6) + (j << 4) + lanelo;
                float d = esq[j] - 2.f * acc[i][j][r];
                unsigned long long p = packDist(d, code);
                if (p < best) best = p;
            }
#pragma unroll
            for (int off = 1; off < 16; off <<= 1) {
                unsigned long long q = __shfl_xor(best, off);
                if (q < best) best = q;
            }
            if (lanelo == 0) {
                int t = row0 + (wm << 6) + (i << 4) + (quad << 2) + r;
                atomicMin(&minpack[t], best);
            }
        }
}

// ---------------- gather quantized + int counts + vq term ----------------
__global__ __launch_bounds__(256) void gather_kernel(
        const float* __restrict__ X, const float* __restrict__ E,
        const unsigned long long* __restrict__ minpack,
        float* __restrict__ out_q, int* __restrict__ icounts,
        float* __restrict__ vqsum) {
    int lane = threadIdx.x & 63;
    int n = (blockIdx.x << 2) + (threadIdx.x >> 6);
    int idx = (int)(minpack[n] & 0xFFFFFFFFULL);
    if (lane == 0) atomicAdd(&icounts[idx], 1);
    const float* xr = X + ((size_t)n << 9);
    const float* er = E + ((size_t)idx << 9);
    float s = 0.f;
#pragma unroll
    for (int i = 0; i < 8; ++i) {
        int c = lane + (i << 6);
        float xv = xr[c], q = er[c];
        out_q[((size_t)n << 9) + c] = q;
        float dlt = xv - q;
        s += dlt * dlt;
    }
    s = waveSum(s);
    if (lane == 0) vqsum[n] = 0.25f * s;
}

// ---------------- codebook: EMA smoothing + perplexity + bucket offsets ----
__global__ __launch_bounds__(1024) void codebook_kernel(
        const float* __restrict__ ema_count, const int* __restrict__ icounts,
        float* __restrict__ out_perp, float* __restrict__ out_newcount,
        int* __restrict__ offsets) {
    __shared__ int sc[1024];
    __shared__ float red[16];
    int tid = threadIdx.x;
    int lane = tid & 63, wid = tid >> 6;
    int ic = icounts[tid];
    sc[tid] = ic;
    for (int off = 1; off < 1024; off <<= 1) {
        __syncthreads();
        int v = (tid >= off) ? sc[tid - off] : 0;
        __syncthreads();
        sc[tid] += v;
    }
    offsets[tid] = sc[tid] - ic;
    __syncthreads();

    float cnt = (float)ic;
    float raw = 0.999f * ema_count[tid] + 0.001f * cnt;
    float v = waveSum(raw);
    if (lane == 0) red[wid] = v;
    __syncthreads();
    float nsum = 0.f;
#pragma unroll
    for (int i = 0; i < 16; ++i) nsum += red[i];
    __syncthreads();
    float p = cnt * (1.f / 32768.f);
    float e = p * logf(p + 1e-10f);
    e = waveSum(e);
    if (lane == 0) red[wid] = e;
    __syncthreads();
    float ent = 0.f;
#pragma unroll
    for (int i = 0; i < 16; ++i) ent += red[i];
    float nc = (raw + 1e-5f) / (nsum + 1024.f * 1e-5f) * nsum;
    out_newcount[tid] = nc;
    if (tid == 0) out_perp[0] = expf(-ent);
}

// ---------------- scatter: token n -> bucket of its code ----------------
__global__ __launch_bounds__(256) void scatter_kernel(
        const unsigned long long* __restrict__ minpack,
        const int* __restrict__ offsets, int* __restrict__ cursor,
        int* __restrict__ bucket) {
    int n = (blockIdx.x << 8) + threadIdx.x;
    int idx = (int)(minpack[n] & 0xFFFFFFFFULL);
    int pos = atomicAdd(&cursor[idx], 1);
    bucket[offsets[idx] + pos] = n;
}

// ---------------- dw[m] = sum of x rows in bucket m (dense reads) ----------
__global__ __launch_bounds__(256) void dw_kernel(
        const float* __restrict__ X, const int* __restrict__ bucket,
        const int* __restrict__ icounts, const int* __restrict__ offsets,
        float* __restrict__ dw) {
    __shared__ float comb[4][512];
    int tid = threadIdx.x, lane = tid & 63, w = tid >> 6;
    int m = blockIdx.x;
    int cnt = icounts[m], base = offsets[m];
    float acc[8] = {};
    for (int i = w; i < cnt; i += 4) {
        int t = bucket[base + i];
        const float* xr = X + ((size_t)t << 9);
#pragma unroll
        for (int j = 0; j < 8; ++j) acc[j] += xr[lane + (j << 6)];
    }
#pragma unroll
    for (int j = 0; j < 8; ++j) comb[w][lane + (j << 6)] = acc[j];
    __syncthreads();
    for (int c = tid; c < 512; c += 256)
        dw[((size_t)m << 9) + c] = comb[0][c] + comb[1][c] + comb[2][c] + comb[3][c];
}

// ---------------- GEMM1 MFMA: Hb = bf16(A1 @ W1T^T), ping-pong pipeline ----
__global__ __launch_bounds__(256) void gemm1_mfma_kernel(
        const unsigned short* __restrict__ A1, const unsigned short* __restrict__ W1T,
        unsigned short* __restrict__ Hb) {
    __shared__ __align__(16) short L[2][2][4096];   // 32 KB
    int tid = threadIdx.x, lane = tid & 63, w = tid >> 6;
    int quad = lane >> 4, lanelo = lane & 15;
    int wm = w >> 1, wn = w & 1;
    int row0 = blockIdx.x << 7, n0 = blockIdx.y << 7;
    f32x4 acc[4][4];
#pragma unroll
    for (int i = 0; i < 4; ++i)
#pragma unroll
        for (int j = 0; j < 4; ++j) acc[i][j] = 0.f;

    stage_tile128(A1, row0, 0, L[0][0], w, lane);
    stage_tile128(W1T, n0, 0, L[0][1], w, lane);

    for (int it = 0; it < 16; ++it) {
        if (it < 15) {
            int kn = (it + 1) << 5, nb = (it + 1) & 1;
            stage_tile128(A1, row0, kn, L[nb][0], w, lane);
            stage_tile128(W1T, n0, kn, L[nb][1], w, lane);
            WAITV(4);
        } else {
            WAITV(0);
        }
        BAR();
        int cb = it & 1;
        short8 af[4], bf[4];
#pragma unroll
        for (int i = 0; i < 4; ++i) {
            int m = (wm << 6) + (i << 4) + lanelo;
            af[i] = *(const short8*)&L[cb][0][(quad << 10) + (m << 3)];
        }
#pragma unroll
        for (int j = 0; j < 4; ++j) {
            int n = (wn << 6) + (j << 4) + lanelo;
            bf[j] = *(const short8*)&L[cb][1][(quad << 10) + (n << 3)];
        }
#pragma unroll
        for (int i = 0; i < 4; ++i)
#pragma unroll
            for (int j = 0; j < 4; ++j) acc[i][j] = mfma16(af[i], bf[j], acc[i][j]);
        BAR();
    }
#pragma unroll
    for (int i = 0; i < 4; ++i)
#pragma unroll
        for (int j = 0; j < 4; ++j)
#pragma unroll
            for (int r = 0; r < 4; ++r) {
                int row = row0 + (wm << 6) + (i << 4) + (quad << 2) + r;
                int col = n0 + (wn << 6) + (j << 4) + lanelo;
                Hb[((size_t)row << 9) + col] = f2bf(acc[i][j][r]);
            }
}

// ---------------- GEMM2 chunk (ping-pong) + softmax partials ---------------
__global__ __launch_bounds__(256) void gemm2_chunk_kernel(
        const unsigned short* __restrict__ A2, const unsigned short* __restrict__ W2T,
        const int* __restrict__ mask, const int* __restrict__ labels,
        float* __restrict__ ws_cmax, float* __restrict__ ws_csum,
        float* __restrict__ ws_lab) {
    __shared__ __align__(16) short L[2][2][4096];
    __shared__ float lmax[2][2][64], lsum[2][2][64], llab[128];
    __shared__ int slab[128];
    int tid = threadIdx.x, lane = tid & 63, w = tid >> 6;
    int quad = lane >> 4, lanelo = lane & 15;
    int wm = w >> 1, wn = w & 1;
    int row0 = blockIdx.x << 7, c0 = blockIdx.y << 7;
    if (tid < 128) {
        int mk = mask[row0 + tid];
        slab[tid] = mk ? 0 : labels[row0 + tid];  // safe label
    }
    __syncthreads();   // slab visible before loop (proper lgkm drain)
    f32x4 acc[4][4];
#pragma unroll
    for (int i = 0; i < 4; ++i)
#pragma unroll
        for (int j = 0; j < 4; ++j) acc[i][j] = 0.f;

    stage_tile128(A2, row0, 0, L[0][0], w, lane);
    stage_tile128(W2T, c0, 0, L[0][1], w, lane);

    for (int it = 0; it < 16; ++it) {
        if (it < 15) {
            int kn = (it + 1) << 5, nb = (it + 1) & 1;
            stage_tile128(A2, row0, kn, L[nb][0], w, lane);
            stage_tile128(W2T, c0, kn, L[nb][1], w, lane);
            WAITV(4);
        } else {
            WAITV(0);
        }
        BAR();
        int cb = it & 1;
        short8 af[4], bf[4];
#pragma unroll
        for (int i = 0; i < 4; ++i) {
            int m = (wm << 6) + (i << 4) + lanelo;
            af[i] = *(const short8*)&L[cb][0][(quad << 10) + (m << 3)];
        }
#pragma unroll
        for (int j = 0; j < 4; ++j) {
            int n = (wn << 6) + (j << 4) + lanelo;
            bf[j] = *(const short8*)&L[cb][1][(quad << 10) + (n << 3)];
        }
#pragma unroll
        for (int i = 0; i < 4; ++i)
#pragma unroll
            for (int j = 0; j < 4; ++j) acc[i][j] = mfma16(af[i], bf[j], acc[i][j]);
        BAR();
    }

    // label-logit capture (unique owner lane/reg)
#pragma unroll
    for (int i = 0; i < 4; ++i)
#pragma unroll
        for (int j = 0; j < 4; ++j)
#pragma unroll
            for (int r = 0; r < 4; ++r) {
                int code = c0 + (wn << 6) + (j << 4) + lanelo;
                int tt = (wm << 6) + (i << 4) + (quad << 2) + r;
                if (code == slab[tt]) llab[tt] = acc[i][j][r];
            }
#pragma unroll
    for (int i = 0; i < 4; ++i)
#pragma unroll
        for (int r = 0; r < 4; ++r) {
            float mx = fmaxf(fmaxf(acc[i][0][r], acc[i][1][r]),
                             fmaxf(acc[i][2][r], acc[i][3][r]));
#pragma unroll
            for (int off = 1; off < 16; off <<= 1) mx = fmaxf(mx, __shfl_xor(mx, off));
            if (lanelo == 0) lmax[wm][wn][(i << 4) + (quad << 2) + r] = mx;
        }
    __syncthreads();
#pragma unroll
    for (int i = 0; i < 4; ++i)
#pragma unroll
        for (int r = 0; r < 4; ++r) {
            int tl = (i << 4) + (quad << 2) + r;
            float cm = fmaxf(lmax[wm][0][tl], lmax[wm][1][tl]);
            float s = expf(acc[i][0][r] - cm) + expf(acc[i][1][r] - cm) +
                      expf(acc[i][2][r] - cm) + expf(acc[i][3][r] - cm);
#pragma unroll
            for (int off = 1; off < 16; off <<= 1) s += __shfl_xor(s, off);
            if (lanelo == 0) lsum[wm][wn][tl] = s;
        }
    __syncthreads();
    if (tid < 128) {
        int wmi = tid >> 6, tl = tid & 63;
        int token = row0 + tid;
        float cm = fmaxf(lmax[wmi][0][tl], lmax[wmi][1][tl]);
        float cs = lsum[wmi][0][tl] + lsum[wmi][1][tl];
        size_t o = ((size_t)blockIdx.y << 15) + token;  // [chunk][token]
        ws_cmax[o] = cm;
        ws_csum[o] = cs;
        if ((slab[tid] >> 7) == (int)blockIdx.y) ws_lab[token] = llab[tid];
    }
}

// ---------------- epilogue: new_weight/new_embedding + CE combine ----------
__global__ __launch_bounds__(256) void epilogue_kernel(
        const float* __restrict__ ema_weight, const float* __restrict__ dw,
        const float* __restrict__ newcount, float* __restrict__ out_neww,
        float* __restrict__ out_newemb,
        const float* __restrict__ ws_cmax, const float* __restrict__ ws_csum,
        const float* __restrict__ ws_lab, const int* __restrict__ mask,
        const float* __restrict__ vqsum, float* __restrict__ loss_out) {
    int bx = blockIdx.x;
    if (bx < 2048) {
        int i = (bx << 8) + threadIdx.x;
        float nw = 0.999f * ema_weight[i] + 0.001f * dw[i];
        out_neww[i] = nw;
        out_newemb[i] = nw / newcount[i >> 9];
    } else {
        int n = ((bx - 2048) << 8) + threadIdx.x;
        float m[8], s[8];
#pragma unroll
        for (int c = 0; c < 8; ++c) {
            m[c] = ws_cmax[(c << 15) + n];
            s[c] = ws_csum[(c << 15) + n];
        }
        float gm = m[0];
#pragma unroll
        for (int c = 1; c < 8; ++c) gm = fmaxf(gm, m[c]);
        float se = 0.f;
#pragma unroll
        for (int c = 0; c < 8; ++c) se += s[c] * expf(m[c] - gm);
        float ce = -(ws_lab[n] - gm - logf(se));
        loss_out[n] = (mask[n] ? 0.f : ce) + vqsum[n];
    }
}

extern "C" void kernel_launch(void* const* d_in, const int* in_sizes, int n_in,
                              void* d_out, int out_size, void* d_ws, size_t ws_size,
                              hipStream_t stream) {
    const float* X          = (const float*)d_in[0];
    const int*   mask       = (const int*)d_in[1];
    const int*   labels     = (const int*)d_in[2];
    const float* E          = (const float*)d_in[3];
    const float* ema_count  = (const float*)d_in[4];
    const float* ema_weight = (const float*)d_in[5];
    const float* g1 = (const float*)d_in[6];
    const float* b1 = (const float*)d_in[7];
    const float* W1 = (const float*)d_in[8];
    const float* g2 = (const float*)d_in[9];
    const float* b2 = (const float*)d_in[10];
    const float* W2 = (const float*)d_in[11];

    float* out = (float*)d_out;
    float* out_q        = out;              // 16777216
    float* out_loss     = out + 16777216;   // 32768
    float* out_perp     = out + 16809984;   // 1
    float* out_newemb   = out + 16809985;   // 524288
    float* out_newcount = out + 17334273;   // 1024
    float* out_neww     = out + 17335297;   // 524288

    float* w = (float*)d_ws;
    float* vqsum = w;  w += 32768;
    float* e_sq = w;   w += 1024;
    float* dwbuf = w;  w += 524288;
    unsigned long long* minpack = (unsigned long long*)w; w += 65536;
    float* ws_cmax = w; w += 262144;
    float* ws_csum = w; w += 262144;
    float* ws_lab  = w; w += 32768;
    int* icounts = (int*)w; w += 1024;      // icounts+cursor contiguous zero region
    int* cursor  = (int*)w; w += 1024;
    int* offsets = (int*)w; w += 1024;
    int* bucket  = (int*)w; w += 32768;
    unsigned short* Ehf = (unsigned short*)w; w += 262144;
    unsigned short* Elf = (unsigned short*)w; w += 262144;
    unsigned short* W1T = (unsigned short*)w; w += 131072;
    unsigned short* W2T = (unsigned short*)w; w += 262144;
    unsigned short* Xf  = (unsigned short*)w; w += 8388608;
    unsigned short* A1  = (unsigned short*)w; w += 8388608;
    unsigned short* Hb  = (unsigned short*)w; w += 8388608;
    unsigned short* A2  = Xf;   // alias: Xf dead after dist

    prep_e_kernel<<<256, 256, 0, stream>>>(E, Ehf, Elf, e_sq, icounts);
    prep_wt_kernel<<<dim3(48, 16), 256, 0, stream>>>(W1, W2, W1T, W2T);
    prep_x_kernel<<<8192, 256, 0, stream>>>(X, g1, b1, Xf, A1, minpack);
    dist_mfma_kernel<<<dim3(256, 8), 256, 0, stream>>>(Xf, Ehf, Elf, e_sq, minpack);
    gather_kernel<<<8192, 256, 0, stream>>>(X, E, minpack, out_q, icounts, vqsum);
    codebook_kernel<<<1, 1024, 0, stream>>>(ema_count, icounts, out_perp,
                                            out_newcount, offsets);
    scatter_kernel<<<128, 256, 0, stream>>>(minpack, offsets, cursor, bucket);
    dw_kernel<<<1024, 256, 0, stream>>>(X, bucket, icounts, offsets, dwbuf);
    gemm1_mfma_kernel<<<dim3(256, 4), 256, 0, stream>>>(A1, W1T, Hb);
    prep_h_kernel<<<8192, 256, 0, stream>>>(Hb, g2, b2, A2);
    gemm2_chunk_kernel<<<dim3(256, 8), 256, 0, stream>>>(A2, W2T, mask, labels,
                                                         ws_cmax, ws_csum, ws_lab);
    epilogue_kernel<<<2176, 256, 0, stream>>>(ema_weight, dwbuf, out_newcount,
                                              out_neww, out_newemb,
                                              ws_cmax, ws_csum, ws_lab,
                                              mask, vqsum, out_loss);
}